// Round 30
// baseline (554.927 us; speedup 1.0000x reference)
//
#include <hip/hip_runtime.h>
#include <hip/hip_bf16.h>
#include <math.h>

typedef __hip_bfloat16 bf16;
typedef __attribute__((ext_vector_type(8))) short s16x8;
typedef __attribute__((ext_vector_type(4))) float f32x4;

#define BB 8
#define SS 512
#define EE 768
#define HH 12
#define DD 64
#define FF 3072
#define NTOK (BB * SS)            // 4096
#define NE ((size_t)NTOK * EE)    // 3,145,728

#define TM 128
#define TN 128
#define TK 32

#define QT 64
#define KT 64

#define FLAG_RES  4    // + Rsrc[row,col]
#define FLAG_GELU 8
#define FLAG_FIN  16   // out = (Rsrc + v) * maskq[row]
#define FLAG_CBSD 32   // Cb store [B',H,S,D] bf16
#define FLAG_QKV  128  // self QKV fused epilogue (N=2304)
#define FLAG_KV   256  // cross K|V fused epilogue (N=1536)
#define FLAG_GSEG 512  // gate logits: per-row-seg weights, dual-source A

#define AS1 const __attribute__((address_space(1))) void*
#define AS3 __attribute__((address_space(3))) void*

__device__ __forceinline__ float gelu_new(float x) {
    float u2 = 1.5957691216057308f * (x + 0.044715f * x * x * x);
    return x / (1.0f + __expf(-u2));
}

// ---------------- batched weight transpose+cast + bias concat: ONE launch -----------
__global__ __launch_bounds__(256) void tcast_all_kernel(
    const float* s0, const float* s1, const float* s2, const float* s3,
    const float* s4, const float* s5, const float* s6, const float* s7,
    const float* s8, const float* s9, const float* s10, const float* s11,
    const float* s12,
    bf16* d0, bf16* d1, bf16* d2, bf16* d3, bf16* d4, bf16* d5, bf16* d6,
    bf16* d7, bf16* d8, bf16* d9, bf16* d10, bf16* d11, bf16* d12,
    const float* fckb, const float* fcvb, const float* a0, const float* a1,
    const float* a2, float* kvb, float* gb)
{
    int bid = blockIdx.x;
    int tid = threadIdx.x;
    if (bid >= 12672) {                      // bias tail: 15 blocks
        int i = (bid - 12672) * 256 + tid;
        int seg = i / 768, off = i % 768;
        if (seg == 0)      kvb[off]       = fckb[off];
        else if (seg == 1) kvb[768 + off] = fcvb[off];
        else if (seg == 2) gb[off]        = a0[off];
        else if (seg == 3) gb[768 + off]  = a1[off];
        else               gb[1536 + off] = a2[off];
        return;
    }
    const int start[14] = {0, 576, 1152, 1728, 2304, 2880, 3456, 4032,
                           4608, 5760, 6912, 8064, 10368, 12672};
    const float* srcs[13] = {s0,s1,s2,s3,s4,s5,s6,s7,s8,s9,s10,s11,s12};
    bf16* dsts[13] = {d0,d1,d2,d3,d4,d5,d6,d7,d8,d9,d10,d11,d12};

    int idx = 0;
    #pragma unroll
    for (int i = 1; i < 13; ++i) if (bid >= start[i]) idx = i;
    int R = (idx < 8) ? 768 : (idx < 11) ? 1536 : (idx == 11) ? 768 : 3072;
    int C = (idx < 8) ? 768 : (idx < 11) ? 768 : (idx == 11) ? 3072 : 768;
    const float* src = srcs[idx];
    bf16* dst = dsts[idx];

    int t = bid - start[idx];
    int gx = C >> 5;
    int c0 = (t % gx) << 5;
    int r0 = (t / gx) << 5;

    __shared__ float tb[32][33];
    int x = tid & 31, y = tid >> 5;
    #pragma unroll
    for (int i = 0; i < 4; ++i) {
        int r = y + i * 8;
        tb[r][x] = src[(size_t)(r0 + r) * C + c0 + x];
    }
    __syncthreads();
    #pragma unroll
    for (int i = 0; i < 4; ++i) {
        int c = y + i * 8;
        dst[(size_t)(c0 + c) * R + r0 + x] = __float2bfloat16(tb[x][c]);
    }
}

// ---------------- LayerNorm body ----------------------------------------------------
__device__ __forceinline__ void ln_body(
    const float* __restrict__ x, bf16* __restrict__ y,
    const float* __restrict__ g, const float* __restrict__ bta, int tid)
{
    float v0 = x[tid], v1 = x[tid + 256], v2 = x[tid + 512];
    float s1 = v0 + v1 + v2;
    float s2 = v0 * v0 + v1 * v1 + v2 * v2;
    #pragma unroll
    for (int o = 32; o > 0; o >>= 1) {
        s1 += __shfl_down(s1, o);
        s2 += __shfl_down(s2, o);
    }
    __shared__ float r1[4], r2[4];
    if ((tid & 63) == 0) { r1[tid >> 6] = s1; r2[tid >> 6] = s2; }
    __syncthreads();
    float mean = (r1[0] + r1[1] + r1[2] + r1[3]) * (1.0f / 768.0f);
    float ssq  = (r2[0] + r2[1] + r2[2] + r2[3]) * (1.0f / 768.0f);
    float rstd = rsqrtf(ssq - mean * mean + 1e-5f);
    y[tid]       = __float2bfloat16((v0 - mean) * rstd * g[tid]       + bta[tid]);
    y[tid + 256] = __float2bfloat16((v1 - mean) * rstd * g[tid + 256] + bta[tid + 256]);
    y[tid + 512] = __float2bfloat16((v2 - mean) * rstd * g[tid + 512] + bta[tid + 512]);
}

__global__ __launch_bounds__(256) void ln_kernel(
    const float* __restrict__ in, bf16* __restrict__ out,
    const float* __restrict__ g, const float* __restrict__ bta)
{
    int row = blockIdx.x;
    ln_body(in + (size_t)row * EE, out + (size_t)row * EE, g, bta, threadIdx.x);
}

__global__ __launch_bounds__(256) void ln_all_kernel(
    const float* __restrict__ x, const float* __restrict__ enc,
    bf16* __restrict__ outx, bf16* __restrict__ outenc,
    const float* __restrict__ g, const float* __restrict__ bta)
{
    int row = blockIdx.x;
    if (row < NTOK) {
        ln_body(x + (size_t)row * EE, outx + (size_t)row * EE, g, bta, threadIdx.x);
    } else {
        int r = row - NTOK;
        int idx = r >> 12, b = (r >> 9) & 7, s = r & 511;
        ln_body(enc + (((size_t)b * 3 + idx) * SS + s) * EE,
                outenc + (size_t)r * EE, g, bta, threadIdx.x);
    }
}

// ---------------- bf16 MFMA GEMM body: TK=32, 3-deep ring, counted vmcnt ------------
template <int FLAGS>
__device__ __forceinline__ void mgemm_body(
    int bx, int by, bf16* smem,
    const bf16* __restrict__ A, const bf16* __restrict__ A2,
    const bf16* __restrict__ Wt, const float* __restrict__ bias,
    float* __restrict__ Cf, bf16* __restrict__ Cb, bf16* __restrict__ Cb2,
    int ldcb, const float* __restrict__ Rsrc, const float* __restrict__ maskq,
    int Nn, int K, int lda)
{
    constexpr bool f_res  = FLAGS & FLAG_RES;
    constexpr bool f_gelu = FLAGS & FLAG_GELU;
    constexpr bool f_fin  = FLAGS & FLAG_FIN;
    constexpr bool f_cbsd = FLAGS & FLAG_CBSD;
    constexpr bool f_qkv  = FLAGS & FLAG_QKV;
    constexpr bool f_kv   = FLAGS & FLAG_KV;
    constexpr bool f_gseg = FLAGS & FLAG_GSEG;

    const int BUFE = TM * TK + TN * TK;      // 8192 elems = 16 KB per buffer
    int tid = threadIdx.x;
    int w = tid >> 6, l = tid & 63;
    int row0 = bx * TM, col0 = by * TN;

    int wr = (w >> 1) * 64, wc = (w & 1) * 64;
    int lr = l & 15, lg = l >> 4;

    const bf16* Wb = Wt;
    const float* bb_ = bias;
    if constexpr (f_gseg) {
        int seg = row0 >> 12;
        Wb = Wt + (size_t)seg * 1536 * 768;
        bb_ = bias + seg * 768;
    }

    f32x4 acc[4][4];
    #pragma unroll
    for (int m = 0; m < 4; ++m)
        #pragma unroll
        for (int n = 0; n < 4; ++n) acc[m][n] = (f32x4){0.f, 0.f, 0.f, 0.f};

    // stage one 128x32 A + 128x32 B tile: 4 loads/thread total.
    auto stage = [&](int buf, int kb) {
        bf16* As_ = smem + buf * BUFE;
        bf16* Bs_ = As_ + TM * TK;
        #pragma unroll
        for (int i = 0; i < 2; ++i) {
            int e = (i * 256 + tid) * 8;           // linear elem pos in 128x32 tile
            int r = e >> 5;
            int c = (e & 31) ^ ((r & 3) << 3);     // pre-swizzled source col
            const bf16* asrc;
            if constexpr (f_gseg) {
                int kg = kb + c;
                if (kg < 768) asrc = A  + (size_t)((row0 + r) & 4095) * lda + kg;
                else          asrc = A2 + (size_t)(row0 + r) * lda + (kg - 768);
            } else {
                asrc = A + (size_t)(row0 + r) * lda + kb + c;
            }
            __builtin_amdgcn_global_load_lds((AS1)asrc,
                (AS3)((char*)As_ + i * 4096 + w * 1024), 16, 0, 0);
            __builtin_amdgcn_global_load_lds((AS1)(Wb + (size_t)(col0 + r) * K + kb + c),
                (AS3)((char*)Bs_ + i * 4096 + w * 1024), 16, 0, 0);
        }
    };

    int nk = K / TK;          // 24 / 48 / 96 — always >= 3
    stage(0, 0);
    stage(1, TK);
    stage(2, 2 * TK);         // 12 loads in flight per wave

    for (int t = 0; t < nk; ++t) {
        int cur = t % 3;
        int ahead = nk - 1 - t; if (ahead > 2) ahead = 2;
        if (ahead == 2)      asm volatile("s_waitcnt vmcnt(8)" ::: "memory");
        else if (ahead == 1) asm volatile("s_waitcnt vmcnt(4)" ::: "memory");
        else                 asm volatile("s_waitcnt vmcnt(0)" ::: "memory");
        __builtin_amdgcn_s_barrier();          // buf[cur] fully staged block-wide

        const char* As = (const char*)(smem + cur * BUFE);
        const char* Bs = As + TM * TK * 2;     // bytes
        s16x8 af[4], bfr[4];
        #pragma unroll
        for (int m = 0; m < 4; ++m) {
            int row = wr + m * 16 + lr;
            af[m] = *(const s16x8*)(As + row * 64 +
                      ((lg * 16) ^ ((row & 3) << 4)));
        }
        #pragma unroll
        for (int n = 0; n < 4; ++n) {
            int row = wc + n * 16 + lr;
            bfr[n] = *(const s16x8*)(Bs + row * 64 +
                      ((lg * 16) ^ ((row & 3) << 4)));
        }
        #pragma unroll
        for (int m = 0; m < 4; ++m)
            #pragma unroll
            for (int n = 0; n < 4; ++n)
                acc[m][n] = __builtin_amdgcn_mfma_f32_16x16x32_bf16(
                    af[m], bfr[n], acc[m][n], 0, 0, 0);

        asm volatile("s_waitcnt lgkmcnt(0)" ::: "memory");   // reads of cur in regs
        __builtin_amdgcn_s_barrier();                        // cur reusable
        if (t + 3 < nk) stage(cur, (t + 3) * TK);            // refill freed buffer
    }

    int gh0 = (col0 + wc) >> 6;

    if constexpr (f_qkv || f_kv || f_cbsd) {
        // ---- coalesced BHSD epilogue via per-wave 8KB LDS tiles (smem dead) ----
        bool vquad = (f_qkv && gh0 >= 24) || (f_kv && gh0 >= 12);
        bf16* Tb = smem + w * 4096;          // per-wave 8KB bf16
        int bb = (row0 + wr) >> 9;
        int s0 = (row0 + wr) & 511;

        // phase 1: bf16 staging
        #pragma unroll
        for (int m = 0; m < 4; ++m)
            #pragma unroll
            for (int n = 0; n < 4; ++n)
                #pragma unroll
                for (int j = 0; j < 4; ++j) {
                    int col = col0 + wc + n * 16 + lr;
                    float v = acc[m][n][j];
                    if (bb_) v += bb_[col];
                    int rl = m * 16 + lg * 4 + j, cl = n * 16 + lr;
                    if (vquad)
                        *(bf16*)((char*)Tb + cl * 128 + ((rl * 2) ^ ((cl & 7) << 4))) =
                            __float2bfloat16(v);
                    else
                        Tb[rl * 64 + (cl ^ ((rl & 7) << 3))] = __float2bfloat16(v);
                }
        if (vquad) {     // V^T [B',H,D,S] — coalesced
            int hV = gh0 - (f_qkv ? 24 : 12);
            bf16* vb = Cb2 + (((size_t)bb * HH + hV) * DD) * SS + s0;
            #pragma unroll
            for (int p = 0; p < 8; ++p) {
                int dl = p * 8 + (l >> 3);
                int ch = l & 7;
                int cs = ch ^ (dl & 7);
                s16x8 vv = *(const s16x8*)((char*)Tb + dl * 128 + cs * 16);
                *(s16x8*)(vb + (size_t)dl * SS + ch * 8) = vv;
            }
            if constexpr (f_qkv) {
                // phase 1b: V BHSD bf16 copy (for present upcast); reuse Tb
                asm volatile("s_waitcnt lgkmcnt(0)" ::: "memory");  // V^T reads done
                #pragma unroll
                for (int m = 0; m < 4; ++m)
                    #pragma unroll
                    for (int n = 0; n < 4; ++n)
                        #pragma unroll
                        for (int j = 0; j < 4; ++j) {
                            int rl = m * 16 + lg * 4 + j, cl = n * 16 + lr;
                            Tb[rl * 64 + (cl ^ ((rl & 7) << 3))] =
                                __float2bfloat16(acc[m][n][j]);
                        }
                bf16* vbhsd = (bf16*)Cf;   // Cf slot reused as bf16 V-BHSD buffer
                bf16* dst2 = vbhsd + (((size_t)bb * HH + hV) * SS + s0) * DD;
                #pragma unroll
                for (int p = 0; p < 8; ++p) {
                    int rl = p * 8 + (l >> 3);
                    int c8 = (l & 7) * 8;
                    s16x8 vv = *(const s16x8*)&Tb[rl * 64 + (c8 ^ ((rl & 7) << 3))];
                    *(s16x8*)(dst2 + (size_t)rl * DD + c8) = vv;
                }
            }
        } else {         // [B',H,S,D] bf16 rows: 8 lanes x 16B = 128B per token-row
            bf16* dst;
            if constexpr (f_qkv)
                dst = (gh0 < 12)
                    ? Cb + (((size_t)bb * HH + gh0) * SS + s0) * DD
                    : Cb + NE + (((size_t)bb * HH + (gh0 - 12)) * SS + s0) * DD;
            else
                dst = Cb + (((size_t)bb * HH + gh0) * SS + s0) * DD;
            #pragma unroll
            for (int p = 0; p < 8; ++p) {
                int rl = p * 8 + (l >> 3);
                int c8 = (l & 7) * 8;
                s16x8 vv = *(const s16x8*)&Tb[rl * 64 + (c8 ^ ((rl & 7) << 3))];
                *(s16x8*)(dst + (size_t)rl * DD + c8) = vv;
            }
        }
    } else {
        // ---- linear epilogues (RES / GELU / FIN / GSEG / plain) ----
        #pragma unroll
        for (int m = 0; m < 4; ++m) {
            #pragma unroll
            for (int n = 0; n < 4; ++n) {
                #pragma unroll
                for (int j = 0; j < 4; ++j) {
                    int row = row0 + wr + m * 16 + lg * 4 + j;
                    int col = col0 + wc + n * 16 + lr;
                    size_t lin = (size_t)row * Nn + col;
                    float v = acc[m][n][j];
                    if (bb_)                 v += bb_[col];
                    if constexpr (f_res)     v += Rsrc[lin];
                    if constexpr (f_gelu)    v = gelu_new(v);
                    if constexpr (f_fin)     v = (Rsrc[lin] + v) * maskq[row];
                    if (Cf) Cf[lin] = v;
                    if (Cb) Cb[(size_t)row * ldcb + col] = __float2bfloat16(v);
                }
            }
        }
    }
}

template <int FLAGS>
__global__ __launch_bounds__(256) void mgemm_kernel(
    const bf16* __restrict__ A, const bf16* __restrict__ A2,
    const bf16* __restrict__ Wt, const float* __restrict__ bias,
    float* __restrict__ Cf, bf16* __restrict__ Cb, bf16* __restrict__ Cb2,
    int ldcb, const float* __restrict__ Rsrc, const float* __restrict__ maskq,
    int Nn, int K, int lda)
{
    __shared__ __align__(16) bf16 smem[3 * (TM * TK + TN * TK)];   // 48 KB ring
    mgemm_body<FLAGS>(blockIdx.x, blockIdx.y, smem, A, A2, Wt, bias,
                      Cf, Cb, Cb2, ldcb, Rsrc, maskq, Nn, K, lda);
}

// ---------------- self-QKV GEMM only (576 blocks) -----------------------------------
__global__ __launch_bounds__(256) void qkv_kernel(
    const bf16* __restrict__ lnb, const bf16* __restrict__ WqkvT,
    bf16* __restrict__ vbhsd, bf16* __restrict__ qbhb, bf16* __restrict__ vbhb)
{
    __shared__ __align__(16) bf16 smem[3 * (TM * TK + TN * TK)];
    mgemm_body<FLAG_QKV>(blockIdx.x & 31, blockIdx.x >> 5, smem, lnb, nullptr,
                         WqkvT, nullptr, (float*)vbhsd, qbhb, vbhb, 0,
                         nullptr, nullptr, 2304, 768, 768);
}

// ---------------- bf16 MFMA flash attention body ------------------------------------
__device__ __forceinline__ void fattn_body(
    int bh, int qt, bf16* sm,
    const bf16* __restrict__ Qb, const bf16* __restrict__ Kb,
    const bf16* __restrict__ Vb, const int* __restrict__ maskE,
    bf16* __restrict__ Out, int causal)
{
    int bp = bh / HH, h = bh % HH;
    int bq = bp & 7;
    int tid = threadIdx.x;
    int w = tid >> 6, l = tid & 63;
    int lr = l & 15, g = l >> 4;

    bf16* Qs = sm;
    bf16* Ks = sm + 4096;
    bf16* Vs = sm + 8192;
    bf16* Ps = sm + 12288;

    int p0 = w * 1024 + l * 16;
    {
        const char* qg = (const char*)(Qb + (((size_t)bq * HH + h) * SS + qt * QT) * DD);
        #pragma unroll
        for (int i = 0; i < 2; ++i) {
            int p = i * 4096 + p0;
            int row = p >> 7, cb = p & 127;
            int scb = cb ^ ((row & 7) << 4);
            __builtin_amdgcn_global_load_lds((AS1)(qg + row * 128 + scb),
                (AS3)((char*)Qs + i * 4096 + w * 1024), 16, 0, 0);
        }
    }

    float mrun[4], lrun[4];
    f32x4 oacc[4];
    #pragma unroll
    for (int j = 0; j < 4; ++j) { mrun[j] = -3.0e38f; lrun[j] = 0.f; }
    #pragma unroll
    for (int n = 0; n < 4; ++n) oacc[n] = (f32x4){0.f, 0.f, 0.f, 0.f};

    int ntiles = causal ? (qt + 1) : (SS / KT);
    int qrow_base = w * 16;

    for (int kt = 0; kt < ntiles; ++kt) {
        const char* kg = (const char*)(Kb + ((size_t)bh * SS + kt * KT) * DD);
        const char* vg = (const char*)(Vb + (size_t)bh * DD * SS + (size_t)kt * KT);
        #pragma unroll
        for (int i = 0; i < 2; ++i) {
            int p = i * 4096 + p0;
            int row = p >> 7, cb = p & 127;
            int scb = cb ^ ((row & 7) << 4);
            __builtin_amdgcn_global_load_lds((AS1)(kg + row * 128 + scb),
                (AS3)((char*)Ks + i * 4096 + w * 1024), 16, 0, 0);
            __builtin_amdgcn_global_load_lds((AS1)(vg + (size_t)row * (SS * 2) + scb),
                (AS3)((char*)Vs + i * 4096 + w * 1024), 16, 0, 0);
        }
        int km[4];
        if (maskE) {
            #pragma unroll
            for (int n = 0; n < 4; ++n)
                km[n] = maskE[(size_t)bq * SS + kt * KT + n * 16 + lr];
        }
        __syncthreads();

        f32x4 sacc[4];
        #pragma unroll
        for (int n = 0; n < 4; ++n) sacc[n] = (f32x4){0.f, 0.f, 0.f, 0.f};
        #pragma unroll
        for (int ks = 0; ks < 2; ++ks) {
            int qrow = qrow_base + lr;
            s16x8 aq = *(const s16x8*)((const char*)Qs +
                        qrow * 128 + ((ks * 64 + g * 16) ^ ((qrow & 7) << 4)));
            #pragma unroll
            for (int n = 0; n < 4; ++n) {
                int krow = n * 16 + lr;
                s16x8 bk = *(const s16x8*)((const char*)Ks +
                            krow * 128 + ((ks * 64 + g * 16) ^ ((krow & 7) << 4)));
                sacc[n] = __builtin_amdgcn_mfma_f32_16x16x32_bf16(aq, bk, sacc[n], 0, 0, 0);
            }
        }

        #pragma unroll
        for (int n = 0; n < 4; ++n) {
            #pragma unroll
            for (int j = 0; j < 4; ++j) {
                float v = sacc[n][j] * 0.125f;
                if (causal) {
                    if (kt == qt && (n * 16 + lr > qrow_base + 4 * g + j)) v = -3.0e38f;
                } else {
                    if (km[n] != 0) v = -1e4f;
                }
                sacc[n][j] = v;
            }
        }

        float mx[4];
        #pragma unroll
        for (int j = 0; j < 4; ++j)
            mx[j] = fmaxf(fmaxf(sacc[0][j], sacc[1][j]), fmaxf(sacc[2][j], sacc[3][j]));
        #pragma unroll
        for (int msk = 1; msk < 16; msk <<= 1) {
            #pragma unroll
            for (int j = 0; j < 4; ++j) mx[j] = fmaxf(mx[j], __shfl_xor(mx[j], msk));
        }
        float rs[4], psum[4];
        #pragma unroll
        for (int j = 0; j < 4; ++j) {
            float mn = fmaxf(mrun[j], mx[j]);
            rs[j] = __expf(mrun[j] - mn);
            mrun[j] = mn;
            psum[j] = 0.f;
        }
        #pragma unroll
        for (int n = 0; n < 4; ++n) {
            #pragma unroll
            for (int j = 0; j < 4; ++j) {
                float p = __expf(sacc[n][j] - mrun[j]);
                psum[j] += p;
                int prow = qrow_base + 4 * g + j;
                int key = n * 16 + lr;
                *(bf16*)((char*)Ps + prow * 128 + ((2 * key) ^ ((prow & 7) << 4))) =
                    __float2bfloat16(p);
            }
        }
        #pragma unroll
        for (int msk = 1; msk < 16; msk <<= 1) {
            #pragma unroll
            for (int j = 0; j < 4; ++j) psum[j] += __shfl_xor(psum[j], msk);
        }
        #pragma unroll
        for (int j = 0; j < 4; ++j) lrun[j] = lrun[j] * rs[j] + psum[j];
        #pragma unroll
        for (int n = 0; n < 4; ++n) {
            #pragma unroll
            for (int j = 0; j < 4; ++j) oacc[n][j] *= rs[j];
        }

        #pragma unroll
        for (int ks = 0; ks < 2; ++ks) {
            int prow = qrow_base + lr;
            s16x8 ap = *(const s16x8*)((const char*)Ps +
                        prow * 128 + ((ks * 64 + g * 16) ^ ((prow & 7) << 4)));
            #pragma unroll
            for (int n = 0; n < 4; ++n) {
                int vrow = n * 16 + lr;
                s16x8 bv = *(const s16x8*)((const char*)Vs +
                            vrow * 128 + ((ks * 64 + g * 16) ^ ((vrow & 7) << 4)));
                oacc[n] = __builtin_amdgcn_mfma_f32_16x16x32_bf16(ap, bv, oacc[n], 0, 0, 0);
            }
        }
        __syncthreads();
    }

    float inv[4];
    #pragma unroll
    for (int j = 0; j < 4; ++j) inv[j] = 1.0f / lrun[j];
    #pragma unroll
    for (int n = 0; n < 4; ++n) {
        #pragma unroll
        for (int j = 0; j < 4; ++j) {
            int q = qt * QT + qrow_base + 4 * g + j;
            int d = n * 16 + lr;
            Out[((size_t)bp * SS + q) * EE + h * DD + d] =
                __float2bfloat16(oacc[n][j] * inv[j]);
        }
    }
}

// cross attention: 2D grid (bh, qt) — same-bh blocks 288 apart (==0 mod 8)
__global__ __launch_bounds__(256) void fattn2_kernel(
    const bf16* __restrict__ Qb, const bf16* __restrict__ Kb,
    const bf16* __restrict__ Vb, const int* __restrict__ maskE,
    bf16* __restrict__ Out, int causal)
{
    __shared__ __align__(16) bf16 sm[4 * 4096];
    fattn_body(blockIdx.x, blockIdx.y, sm, Qb, Kb, Vb, maskE, Out, causal);
}

// ---------------- mega2: self-attn (768) ∥ cross-KV GEMM (1152) ∥ cast (1536) -------
// interleaved 2:3:4 per 9-block group so every CU hosts a mix (mutual latency hiding).
// fattn same-bh pairs are 432 dispatch-slots apart (==0 mod 8) -> same XCD preserved.
__global__ __launch_bounds__(256) void fattn_kvcast_kernel(
    const bf16* __restrict__ Qb, const bf16* __restrict__ Kb,
    const bf16* __restrict__ Vb, bf16* __restrict__ Out,
    const bf16* __restrict__ lnenc, const bf16* __restrict__ fckvT,
    const float* __restrict__ kvb,
    bf16* __restrict__ kb_c, bf16* __restrict__ vb_c,
    const bf16* __restrict__ kb, const bf16* __restrict__ vbs,
    float* __restrict__ kp, float* __restrict__ vp)
{
    __shared__ __align__(16) bf16 smem[3 * (TM * TK + TN * TK)];   // 48 KB union
    int bid = blockIdx.x;
    int g9 = bid / 9, r9 = bid % 9;
    if (r9 < 2) {
        int f = g9 * 2 + r9;                 // 0..767
        fattn_body(f % 96, f / 96, smem, Qb, Kb, Vb, nullptr, Out, 1);
    } else if (r9 < 5) {
        int t = g9 * 3 + (r9 - 2);           // 0..1151
        mgemm_body<FLAG_KV>(t % 96, t / 96, smem, lnenc, nullptr, fckvT, kvb,
                            nullptr, kb_c, vb_c, 0, nullptr, nullptr, 1536, 768, 768);
    } else {
        int c = g9 * 4 + (r9 - 5);           // 0..1535
        size_t i = ((size_t)c * 256 + threadIdx.x) * 8;
        s16x8 kv = *(const s16x8*)(kb + i);
        s16x8 vv = *(const s16x8*)(vbs + i);
        #pragma unroll
        for (int j = 0; j < 8; ++j) {
            unsigned int bk = ((unsigned int)(unsigned short)kv[j]) << 16;
            unsigned int bv = ((unsigned int)(unsigned short)vv[j]) << 16;
            kp[i + j] = __uint_as_float(bk);
            vp[i + j] = __uint_as_float(bv);
        }
    }
}

// ---------------- fused gate(3 branches) + /sqrt3*maskq + ln2 (bf16 logits) ---------
__global__ __launch_bounds__(256) void gate3ln_kernel(
    const bf16* __restrict__ logits, const float* __restrict__ a,
    const bf16* __restrict__ e, float* __restrict__ acc, bf16* __restrict__ lnout,
    const int* __restrict__ tau, const float* __restrict__ maskq,
    const float* __restrict__ g, const float* __restrict__ bta)
{
    int row = blockIdx.x;
    int tid = threadIdx.x;
    float thr = (float)tau[0];
    float mq = maskq[row] * 0.57735026918962576f;
    size_t base = (size_t)row * EE;

    float aq[3];
    float s1 = 0.f, s2 = 0.f;
    #pragma unroll
    for (int c = 0; c < 3; ++c) {
        size_t i = base + tid + c * 256;
        float av = a[i];
        float r = 0.f;
        #pragma unroll
        for (int idx = 0; idx < 3; ++idx) {
            float lg = __bfloat162float(logits[(size_t)idx * NE + i]);
            float ev = __bfloat162float(e[(size_t)idx * NE + i]);
            float al = 1.0f / (1.0f + __expf(-lg));
            float lm = (al > thr) ? 1.0f : 0.0f;
            float vm = (al < 1.0f - thr) ? 1.0f : 0.0f;
            r += al * lm * av + (1.0f - al) * vm * ev;
        }
        float v = r * mq;
        acc[i] = v;
        aq[c] = v;
        s1 += v;
        s2 += v * v;
    }
    #pragma unroll
    for (int o = 32; o > 0; o >>= 1) {
        s1 += __shfl_down(s1, o);
        s2 += __shfl_down(s2, o);
    }
    __shared__ float r1[4], r2[4];
    if ((tid & 63) == 0) { r1[tid >> 6] = s1; r2[tid >> 6] = s2; }
    __syncthreads();
    float mean = (r1[0] + r1[1] + r1[2] + r1[3]) * (1.0f / 768.0f);
    float ssq  = (r2[0] + r2[1] + r2[2] + r2[3]) * (1.0f / 768.0f);
    float rstd = rsqrtf(ssq - mean * mean + 1e-5f);

    bf16* y = lnout + base;
    #pragma unroll
    for (int c = 0; c < 3; ++c) {
        int col = tid + c * 256;
        y[col] = __float2bfloat16((aq[c] - mean) * rstd * g[col] + bta[col]);
    }
}

extern "C" void kernel_launch(void* const* d_in, const int* in_sizes, int n_in,
                              void* d_out, int out_size, void* d_ws, size_t ws_size,
                              hipStream_t stream)
{
    const float* x        = (const float*)d_in[0];
    const float* enc      = (const float*)d_in[1];
    const float* maskq    = (const float*)d_in[2];
    const int*   mask_enc = (const int*)d_in[4];
    const int*   tau      = (const int*)d_in[6];
    const float* Wq = (const float*)d_in[7];
    const float* Wk = (const float*)d_in[8];
    const float* Wv = (const float*)d_in[9];
    const float* Wo = (const float*)d_in[10];
    const float* bo = (const float*)d_in[11];
    const float* fcq_w = (const float*)d_in[12];
    const float* fcq_b = (const float*)d_in[13];
    const float* fck_w = (const float*)d_in[14];
    const float* fck_b = (const float*)d_in[15];
    const float* fcv_w = (const float*)d_in[16];
    const float* fcv_b = (const float*)d_in[17];
    const float* cproj_w = (const float*)d_in[18];
    const float* cproj_b = (const float*)d_in[19];
    const float* ln1_g = (const float*)d_in[20];
    const float* ln1_b = (const float*)d_in[21];
    const float* ln2_g = (const float*)d_in[22];
    const float* ln2_b = (const float*)d_in[23];
    const float* cfc_w = (const float*)d_in[24];
    const float* cfc_b = (const float*)d_in[25];
    const float* cproj2_w = (const float*)d_in[26];
    const float* cproj2_b = (const float*)d_in[27];
    const float* aw[3] = {(const float*)d_in[28], (const float*)d_in[30], (const float*)d_in[32]};
    const float* ab[3] = {(const float*)d_in[29], (const float*)d_in[31], (const float*)d_in[33]};

    float* out   = (float*)d_out;       // [NTOK, E]
    float* kpres = out + NE;            // present K [B,H,S,D] f32 (V at +NE)
    float* vpres = out + 2 * NE;

    float* ws  = (float*)d_ws;
    float* a     = ws;                  // NE f32
    float* acc   = ws + NE;             // NE f32
    float* R     = ws + 2 * NE;         // 3*NE f32, time-shared
    bf16*  kb_c    = (bf16*)R;
    bf16*  vb_c    = kb_c + 3 * NE;
    bf16*  logitsb = (bf16*)R;          // [3][NE] bf16 (after cross-attn, kb_c dead)
    bf16*  mlphb   = (bf16*)R;

    bf16* bbase = (bf16*)(ws + 5 * NE);
    bf16* lnb   = bbase;
    bf16* atts  = bbase;
    bf16* lnenc = bbase + NE;
    bf16* attc  = lnenc;
    bf16* a_bf  = bbase + 4 * NE;
    bf16* e_bf  = bbase + 5 * NE;
    bf16* qbhb  = bbase + 8 * NE;
    bf16* kbhb  = bbase + 9 * NE;      // written by QKV as Cb+NE
    bf16* vbhb  = bbase + 10 * NE;     // V^T for attention
    bf16* vbhsd = bbase + 11 * NE;     // V BHSD bf16 copy (for present upcast)
    bf16* wp    = bbase + 12 * NE;
    bf16* WqkvT = wp;          wp += 3 * 768 * 768;
    bf16* WoT = wp;            wp += 768 * 768;
    bf16* fcqT = wp;           wp += 768 * 768;
    bf16* fckvT = wp;          wp += 2 * 768 * 768;
    bf16* cprojT = wp;         wp += 768 * 768;
    bf16* awT = wp;            wp += (size_t)3 * 1536 * 768;
    bf16* cfcT = wp;           wp += (size_t)768 * 3072;
    bf16* cproj2T = wp;        wp += (size_t)3072 * 768;
    float* kvb = (float*)wp;
    float* gb  = kvb + 1536;

    dim3 blk(256);

    // 1. ALL weight prep + bias concat, one launch
    tcast_all_kernel<<<12687, blk, 0, stream>>>(
        Wq, Wk, Wv, Wo, fcq_w, fck_w, fcv_w, cproj_w,
        aw[0], aw[1], aw[2], cfc_w, cproj2_w,
        WqkvT, WqkvT + 768 * 768, WqkvT + 2 * 768 * 768, WoT, fcqT,
        fckvT, fckvT + 768 * 768, cprojT,
        awT, awT + 1536 * 768, awT + 2 * 1536 * 768, cfcT, cproj2T,
        fck_b, fcv_b, ab[0], ab[1], ab[2], kvb, gb);
    // 2. LN(x) + LN(enc), one launch
    ln_all_kernel<<<4 * NTOK, blk, 0, stream>>>(x, enc, lnb, lnenc, ln1_g, ln1_b);
    // 3. self-QKV GEMM only (576 blocks) — unblocks self-attn ASAP
    qkv_kernel<<<576, blk, 0, stream>>>(lnb, WqkvT, vbhsd, qbhb, vbhb);
    // 4. mega2: self-attn ∥ cross-KV GEMM ∥ present cast (independent work, one fill)
    fattn_kvcast_kernel<<<3456, blk, 0, stream>>>(qbhb, kbhb, vbhb, atts,
        lnenc, fckvT, kvb, kb_c, vb_c, kbhb, vbhsd, kpres, vpres);
    // 5. a = attout@Wo + bo + x
    mgemm_kernel<FLAG_RES><<<dim3(32, 6), blk, 0, stream>>>(atts, nullptr, WoT, bo,
        a, a_bf, nullptr, 768, x, nullptr, 768, 768, 768);
    // 6. al = ln1(a)
    ln_kernel<<<NTOK, blk, 0, stream>>>(a, lnb, ln1_g, ln1_b);
    // 7. cross q
    mgemm_kernel<FLAG_CBSD><<<dim3(32, 6), blk, 0, stream>>>(lnb, nullptr, fcqT, fcq_b,
        nullptr, qbhb, nullptr, 0, nullptr, nullptr, 768, 768, 768);
    // 8. cross attention (batched over 3 encoders)
    fattn2_kernel<<<dim3(288, 8), blk, 0, stream>>>(qbhb, kb_c, vb_c, mask_enc, attc, 0);
    // 9. e = attout@cproj + b
    mgemm_kernel<0><<<dim3(96, 6), blk, 0, stream>>>(attc, nullptr, cprojT, cproj_b,
        nullptr, e_bf, nullptr, 768, nullptr, nullptr, 768, 768, 768);
    // 10. gate logits (bf16 out)
    mgemm_kernel<FLAG_GSEG><<<dim3(96, 6), blk, 0, stream>>>(a_bf, e_bf, awT, gb,
        nullptr, logitsb, nullptr, 768, nullptr, nullptr, 768, 1536, 768);
    // 11. gate + ln2
    gate3ln_kernel<<<NTOK, blk, 0, stream>>>(logitsb, a, e_bf, acc, lnb,
        tau, maskq, ln2_g, ln2_b);
    // 12-13. MLP
    mgemm_kernel<FLAG_GELU><<<dim3(32, 24), blk, 0, stream>>>(lnb, nullptr, cfcT, cfc_b,
        nullptr, mlphb, nullptr, 3072, nullptr, nullptr, 3072, 768, 768);
    mgemm_kernel<FLAG_FIN><<<dim3(32, 6), blk, 0, stream>>>(mlphb, nullptr, cproj2T, cproj2_b,
        out, nullptr, nullptr, 0, acc, maskq, 768, 3072, 3072);
}

// Round 31
// 537.488 us; speedup vs baseline: 1.0324x; 1.0324x over previous
//
#include <hip/hip_runtime.h>
#include <hip/hip_bf16.h>
#include <math.h>

typedef __hip_bfloat16 bf16;
typedef __attribute__((ext_vector_type(8))) short s16x8;
typedef __attribute__((ext_vector_type(4))) float f32x4;

#define BB 8
#define SS 512
#define EE 768
#define HH 12
#define DD 64
#define FF 3072
#define NTOK (BB * SS)            // 4096
#define NE ((size_t)NTOK * EE)    // 3,145,728

#define TM 128
#define TN 128
#define TK 32

#define QT 64
#define KT 64

#define FLAG_RES  4    // + Rsrc[row,col]
#define FLAG_GELU 8
#define FLAG_FIN  16   // out = (Rsrc + v) * maskq[row]
#define FLAG_CBSD 32   // Cb store [B',H,S,D] bf16
#define FLAG_QKV  128  // self QKV fused epilogue (N=2304)
#define FLAG_KV   256  // cross K|V fused epilogue (N=1536)
#define FLAG_GSEG 512  // gate logits: per-row-seg weights, dual-source A

#define AS1 const __attribute__((address_space(1))) void*
#define AS3 __attribute__((address_space(3))) void*

__device__ __forceinline__ float gelu_new(float x) {
    float u2 = 1.5957691216057308f * (x + 0.044715f * x * x * x);
    return x / (1.0f + __expf(-u2));
}

// ---------------- batched weight transpose+cast + bias concat: ONE launch -----------
__global__ __launch_bounds__(256) void tcast_all_kernel(
    const float* s0, const float* s1, const float* s2, const float* s3,
    const float* s4, const float* s5, const float* s6, const float* s7,
    const float* s8, const float* s9, const float* s10, const float* s11,
    const float* s12,
    bf16* d0, bf16* d1, bf16* d2, bf16* d3, bf16* d4, bf16* d5, bf16* d6,
    bf16* d7, bf16* d8, bf16* d9, bf16* d10, bf16* d11, bf16* d12,
    const float* fckb, const float* fcvb, const float* a0, const float* a1,
    const float* a2, float* kvb, float* gb)
{
    int bid = blockIdx.x;
    int tid = threadIdx.x;
    if (bid >= 12672) {                      // bias tail: 15 blocks
        int i = (bid - 12672) * 256 + tid;
        int seg = i / 768, off = i % 768;
        if (seg == 0)      kvb[off]       = fckb[off];
        else if (seg == 1) kvb[768 + off] = fcvb[off];
        else if (seg == 2) gb[off]        = a0[off];
        else if (seg == 3) gb[768 + off]  = a1[off];
        else               gb[1536 + off] = a2[off];
        return;
    }
    const int start[14] = {0, 576, 1152, 1728, 2304, 2880, 3456, 4032,
                           4608, 5760, 6912, 8064, 10368, 12672};
    const float* srcs[13] = {s0,s1,s2,s3,s4,s5,s6,s7,s8,s9,s10,s11,s12};
    bf16* dsts[13] = {d0,d1,d2,d3,d4,d5,d6,d7,d8,d9,d10,d11,d12};

    int idx = 0;
    #pragma unroll
    for (int i = 1; i < 13; ++i) if (bid >= start[i]) idx = i;
    int R = (idx < 8) ? 768 : (idx < 11) ? 1536 : (idx == 11) ? 768 : 3072;
    int C = (idx < 8) ? 768 : (idx < 11) ? 768 : (idx == 11) ? 3072 : 768;
    const float* src = srcs[idx];
    bf16* dst = dsts[idx];

    int t = bid - start[idx];
    int gx = C >> 5;
    int c0 = (t % gx) << 5;
    int r0 = (t / gx) << 5;

    __shared__ float tb[32][33];
    int x = tid & 31, y = tid >> 5;
    #pragma unroll
    for (int i = 0; i < 4; ++i) {
        int r = y + i * 8;
        tb[r][x] = src[(size_t)(r0 + r) * C + c0 + x];
    }
    __syncthreads();
    #pragma unroll
    for (int i = 0; i < 4; ++i) {
        int c = y + i * 8;
        dst[(size_t)(c0 + c) * R + r0 + x] = __float2bfloat16(tb[x][c]);
    }
}

// ---------------- LayerNorm body ----------------------------------------------------
__device__ __forceinline__ void ln_body(
    const float* __restrict__ x, bf16* __restrict__ y,
    const float* __restrict__ g, const float* __restrict__ bta, int tid)
{
    float v0 = x[tid], v1 = x[tid + 256], v2 = x[tid + 512];
    float s1 = v0 + v1 + v2;
    float s2 = v0 * v0 + v1 * v1 + v2 * v2;
    #pragma unroll
    for (int o = 32; o > 0; o >>= 1) {
        s1 += __shfl_down(s1, o);
        s2 += __shfl_down(s2, o);
    }
    __shared__ float r1[4], r2[4];
    if ((tid & 63) == 0) { r1[tid >> 6] = s1; r2[tid >> 6] = s2; }
    __syncthreads();
    float mean = (r1[0] + r1[1] + r1[2] + r1[3]) * (1.0f / 768.0f);
    float ssq  = (r2[0] + r2[1] + r2[2] + r2[3]) * (1.0f / 768.0f);
    float rstd = rsqrtf(ssq - mean * mean + 1e-5f);
    y[tid]       = __float2bfloat16((v0 - mean) * rstd * g[tid]       + bta[tid]);
    y[tid + 256] = __float2bfloat16((v1 - mean) * rstd * g[tid + 256] + bta[tid + 256]);
    y[tid + 512] = __float2bfloat16((v2 - mean) * rstd * g[tid + 512] + bta[tid + 512]);
}

__global__ __launch_bounds__(256) void ln_kernel(
    const float* __restrict__ in, bf16* __restrict__ out,
    const float* __restrict__ g, const float* __restrict__ bta)
{
    int row = blockIdx.x;
    ln_body(in + (size_t)row * EE, out + (size_t)row * EE, g, bta, threadIdx.x);
}

__global__ __launch_bounds__(256) void ln_all_kernel(
    const float* __restrict__ x, const float* __restrict__ enc,
    bf16* __restrict__ outx, bf16* __restrict__ outenc,
    const float* __restrict__ g, const float* __restrict__ bta)
{
    int row = blockIdx.x;
    if (row < NTOK) {
        ln_body(x + (size_t)row * EE, outx + (size_t)row * EE, g, bta, threadIdx.x);
    } else {
        int r = row - NTOK;
        int idx = r >> 12, b = (r >> 9) & 7, s = r & 511;
        ln_body(enc + (((size_t)b * 3 + idx) * SS + s) * EE,
                outenc + (size_t)r * EE, g, bta, threadIdx.x);
    }
}

// ---------------- present upcast: kbhb/vbhsd bf16 -> kpres/vpres f32 ---------------
__global__ __launch_bounds__(256) void present_cast_kernel(
    const bf16* __restrict__ kb, const bf16* __restrict__ vb,
    float* __restrict__ kp, float* __restrict__ vp)
{
    size_t i = ((size_t)blockIdx.x * 256 + threadIdx.x) * 8;   // grid covers NE
    s16x8 kv = *(const s16x8*)(kb + i);
    s16x8 vv = *(const s16x8*)(vb + i);
    #pragma unroll
    for (int j = 0; j < 8; ++j) {
        unsigned short uk = (unsigned short)kv[j];
        unsigned short uv = (unsigned short)vv[j];
        unsigned int bk = ((unsigned int)uk) << 16;
        unsigned int bv = ((unsigned int)uv) << 16;
        kp[i + j] = __uint_as_float(bk);
        vp[i + j] = __uint_as_float(bv);
    }
}

// ---------------- bf16 MFMA GEMM body: TK=32, 3-deep ring, counted vmcnt ------------
template <int FLAGS>
__device__ __forceinline__ void mgemm_body(
    int bx, int by, bf16* smem,
    const bf16* __restrict__ A, const bf16* __restrict__ A2,
    const bf16* __restrict__ Wt, const float* __restrict__ bias,
    float* __restrict__ Cf, bf16* __restrict__ Cb, bf16* __restrict__ Cb2,
    int ldcb, const float* __restrict__ Rsrc, const float* __restrict__ maskq,
    int Nn, int K, int lda)
{
    constexpr bool f_res  = FLAGS & FLAG_RES;
    constexpr bool f_gelu = FLAGS & FLAG_GELU;
    constexpr bool f_fin  = FLAGS & FLAG_FIN;
    constexpr bool f_cbsd = FLAGS & FLAG_CBSD;
    constexpr bool f_qkv  = FLAGS & FLAG_QKV;
    constexpr bool f_kv   = FLAGS & FLAG_KV;
    constexpr bool f_gseg = FLAGS & FLAG_GSEG;

    const int BUFE = TM * TK + TN * TK;      // 8192 elems = 16 KB per buffer
    int tid = threadIdx.x;
    int w = tid >> 6, l = tid & 63;
    int row0 = bx * TM, col0 = by * TN;

    int wr = (w >> 1) * 64, wc = (w & 1) * 64;
    int lr = l & 15, lg = l >> 4;

    const bf16* Wb = Wt;
    const float* bb_ = bias;
    if constexpr (f_gseg) {
        int seg = row0 >> 12;
        Wb = Wt + (size_t)seg * 1536 * 768;
        bb_ = bias + seg * 768;
    }

    f32x4 acc[4][4];
    #pragma unroll
    for (int m = 0; m < 4; ++m)
        #pragma unroll
        for (int n = 0; n < 4; ++n) acc[m][n] = (f32x4){0.f, 0.f, 0.f, 0.f};

    // stage one 128x32 A + 128x32 B tile: 4 loads/thread total.
    auto stage = [&](int buf, int kb) {
        bf16* As_ = smem + buf * BUFE;
        bf16* Bs_ = As_ + TM * TK;
        #pragma unroll
        for (int i = 0; i < 2; ++i) {
            int e = (i * 256 + tid) * 8;           // linear elem pos in 128x32 tile
            int r = e >> 5;
            int c = (e & 31) ^ ((r & 3) << 3);     // pre-swizzled source col
            const bf16* asrc;
            if constexpr (f_gseg) {
                int kg = kb + c;
                if (kg < 768) asrc = A  + (size_t)((row0 + r) & 4095) * lda + kg;
                else          asrc = A2 + (size_t)(row0 + r) * lda + (kg - 768);
            } else {
                asrc = A + (size_t)(row0 + r) * lda + kb + c;
            }
            __builtin_amdgcn_global_load_lds((AS1)asrc,
                (AS3)((char*)As_ + i * 4096 + w * 1024), 16, 0, 0);
            __builtin_amdgcn_global_load_lds((AS1)(Wb + (size_t)(col0 + r) * K + kb + c),
                (AS3)((char*)Bs_ + i * 4096 + w * 1024), 16, 0, 0);
        }
    };

    int nk = K / TK;          // 24 / 48 / 96 — always >= 3
    stage(0, 0);
    stage(1, TK);
    stage(2, 2 * TK);         // 12 loads in flight per wave

    for (int t = 0; t < nk; ++t) {
        int cur = t % 3;
        int ahead = nk - 1 - t; if (ahead > 2) ahead = 2;
        if (ahead == 2)      asm volatile("s_waitcnt vmcnt(8)" ::: "memory");
        else if (ahead == 1) asm volatile("s_waitcnt vmcnt(4)" ::: "memory");
        else                 asm volatile("s_waitcnt vmcnt(0)" ::: "memory");
        __builtin_amdgcn_s_barrier();          // buf[cur] fully staged block-wide

        const char* As = (const char*)(smem + cur * BUFE);
        const char* Bs = As + TM * TK * 2;     // bytes
        s16x8 af[4], bfr[4];
        #pragma unroll
        for (int m = 0; m < 4; ++m) {
            int row = wr + m * 16 + lr;
            af[m] = *(const s16x8*)(As + row * 64 +
                      ((lg * 16) ^ ((row & 3) << 4)));
        }
        #pragma unroll
        for (int n = 0; n < 4; ++n) {
            int row = wc + n * 16 + lr;
            bfr[n] = *(const s16x8*)(Bs + row * 64 +
                      ((lg * 16) ^ ((row & 3) << 4)));
        }
        #pragma unroll
        for (int m = 0; m < 4; ++m)
            #pragma unroll
            for (int n = 0; n < 4; ++n)
                acc[m][n] = __builtin_amdgcn_mfma_f32_16x16x32_bf16(
                    af[m], bfr[n], acc[m][n], 0, 0, 0);

        asm volatile("s_waitcnt lgkmcnt(0)" ::: "memory");   // reads of cur in regs
        __builtin_amdgcn_s_barrier();                        // cur reusable
        if (t + 3 < nk) stage(cur, (t + 3) * TK);            // refill freed buffer
    }

    int gh0 = (col0 + wc) >> 6;

    if constexpr (f_qkv || f_kv || f_cbsd) {
        // ---- coalesced BHSD epilogue via per-wave 8KB LDS tiles (smem dead) ----
        bool vquad = (f_qkv && gh0 >= 24) || (f_kv && gh0 >= 12);
        bf16* Tb = smem + w * 4096;          // per-wave 8KB bf16
        int bb = (row0 + wr) >> 9;
        int s0 = (row0 + wr) & 511;

        // phase 1: bf16 staging
        #pragma unroll
        for (int m = 0; m < 4; ++m)
            #pragma unroll
            for (int n = 0; n < 4; ++n)
                #pragma unroll
                for (int j = 0; j < 4; ++j) {
                    int col = col0 + wc + n * 16 + lr;
                    float v = acc[m][n][j];
                    if (bb_) v += bb_[col];
                    int rl = m * 16 + lg * 4 + j, cl = n * 16 + lr;
                    if (vquad)
                        *(bf16*)((char*)Tb + cl * 128 + ((rl * 2) ^ ((cl & 7) << 4))) =
                            __float2bfloat16(v);
                    else
                        Tb[rl * 64 + (cl ^ ((rl & 7) << 3))] = __float2bfloat16(v);
                }
        if (vquad) {     // V^T [B',H,D,S] — coalesced
            int hV = gh0 - (f_qkv ? 24 : 12);
            bf16* vb = Cb2 + (((size_t)bb * HH + hV) * DD) * SS + s0;
            #pragma unroll
            for (int p = 0; p < 8; ++p) {
                int dl = p * 8 + (l >> 3);
                int ch = l & 7;
                int cs = ch ^ (dl & 7);
                s16x8 vv = *(const s16x8*)((char*)Tb + dl * 128 + cs * 16);
                *(s16x8*)(vb + (size_t)dl * SS + ch * 8) = vv;
            }
            if constexpr (f_qkv) {
                // phase 1b: V BHSD bf16 copy (for present upcast); reuse Tb
                asm volatile("s_waitcnt lgkmcnt(0)" ::: "memory");  // V^T reads done
                #pragma unroll
                for (int m = 0; m < 4; ++m)
                    #pragma unroll
                    for (int n = 0; n < 4; ++n)
                        #pragma unroll
                        for (int j = 0; j < 4; ++j) {
                            int rl = m * 16 + lg * 4 + j, cl = n * 16 + lr;
                            Tb[rl * 64 + (cl ^ ((rl & 7) << 3))] =
                                __float2bfloat16(acc[m][n][j]);
                        }
                bf16* vbhsd = (bf16*)Cf;   // Cf slot reused as bf16 V-BHSD buffer
                bf16* dst2 = vbhsd + (((size_t)bb * HH + hV) * SS + s0) * DD;
                #pragma unroll
                for (int p = 0; p < 8; ++p) {
                    int rl = p * 8 + (l >> 3);
                    int c8 = (l & 7) * 8;
                    s16x8 vv = *(const s16x8*)&Tb[rl * 64 + (c8 ^ ((rl & 7) << 3))];
                    *(s16x8*)(dst2 + (size_t)rl * DD + c8) = vv;
                }
            }
        } else {         // [B',H,S,D] bf16 rows: 8 lanes x 16B = 128B per token-row
            bf16* dst;
            if constexpr (f_qkv)
                dst = (gh0 < 12)
                    ? Cb + (((size_t)bb * HH + gh0) * SS + s0) * DD
                    : Cb + NE + (((size_t)bb * HH + (gh0 - 12)) * SS + s0) * DD;
            else
                dst = Cb + (((size_t)bb * HH + gh0) * SS + s0) * DD;
            #pragma unroll
            for (int p = 0; p < 8; ++p) {
                int rl = p * 8 + (l >> 3);
                int c8 = (l & 7) * 8;
                s16x8 vv = *(const s16x8*)&Tb[rl * 64 + (c8 ^ ((rl & 7) << 3))];
                *(s16x8*)(dst + (size_t)rl * DD + c8) = vv;
            }
        }
    } else {
        // ---- linear epilogues (RES / GELU / FIN / GSEG / plain) ----
        #pragma unroll
        for (int m = 0; m < 4; ++m) {
            #pragma unroll
            for (int n = 0; n < 4; ++n) {
                #pragma unroll
                for (int j = 0; j < 4; ++j) {
                    int row = row0 + wr + m * 16 + lg * 4 + j;
                    int col = col0 + wc + n * 16 + lr;
                    size_t lin = (size_t)row * Nn + col;
                    float v = acc[m][n][j];
                    if (bb_)                 v += bb_[col];
                    if constexpr (f_res)     v += Rsrc[lin];
                    if constexpr (f_gelu)    v = gelu_new(v);
                    if constexpr (f_fin)     v = (Rsrc[lin] + v) * maskq[row];
                    if (Cf) Cf[lin] = v;
                    if (Cb) Cb[(size_t)row * ldcb + col] = __float2bfloat16(v);
                }
            }
        }
    }
}

template <int FLAGS>
__global__ __launch_bounds__(256) void mgemm_kernel(
    const bf16* __restrict__ A, const bf16* __restrict__ A2,
    const bf16* __restrict__ Wt, const float* __restrict__ bias,
    float* __restrict__ Cf, bf16* __restrict__ Cb, bf16* __restrict__ Cb2,
    int ldcb, const float* __restrict__ Rsrc, const float* __restrict__ maskq,
    int Nn, int K, int lda)
{
    __shared__ __align__(16) bf16 smem[3 * (TM * TK + TN * TK)];   // 48 KB ring
    mgemm_body<FLAGS>(blockIdx.x, blockIdx.y, smem, A, A2, Wt, bias,
                      Cf, Cb, Cb2, ldcb, Rsrc, maskq, Nn, K, lda);
}

// ---------------- mega: self-QKV (576 blocks) + cross-KV (1152 blocks) --------------
__global__ __launch_bounds__(256) void qkvkv_kernel(
    const bf16* __restrict__ lnb, const bf16* __restrict__ lnenc,
    const bf16* __restrict__ WqkvT, const bf16* __restrict__ fckvT,
    const float* __restrict__ kvb,
    bf16* __restrict__ vbhsd, bf16* __restrict__ qbhb, bf16* __restrict__ vbhb,
    bf16* __restrict__ kb_c, bf16* __restrict__ vb_c)
{
    __shared__ __align__(16) bf16 smem[3 * (TM * TK + TN * TK)];
    int bid = blockIdx.x;
    if (bid < 576) {
        mgemm_body<FLAG_QKV>(bid & 31, bid >> 5, smem, lnb, nullptr, WqkvT, nullptr,
                             (float*)vbhsd, qbhb, vbhb, 0, nullptr, nullptr, 2304, 768, 768);
    } else {
        int t = bid - 576;
        mgemm_body<FLAG_KV>(t % 96, t / 96, smem, lnenc, nullptr, fckvT, kvb,
                            nullptr, kb_c, vb_c, 0, nullptr, nullptr, 1536, 768, 768);
    }
}

// ---------------- bf16 MFMA flash attention -----------------------------------------
// grid (bh, qt): same-bh blocks are 96/288 apart (==0 mod 8) -> same XCD -> K/V L2-local.
__global__ __launch_bounds__(256) void fattn2_kernel(
    const bf16* __restrict__ Qb, const bf16* __restrict__ Kb,
    const bf16* __restrict__ Vb, const int* __restrict__ maskE,
    bf16* __restrict__ Out, int causal)
{
    int bh = blockIdx.x, qt = blockIdx.y;
    int bp = bh / HH, h = bh % HH;
    int bq = bp & 7;
    int tid = threadIdx.x;
    int w = tid >> 6, l = tid & 63;
    int lr = l & 15, g = l >> 4;

    __shared__ __align__(16) bf16 Qs[64 * 64];
    __shared__ __align__(16) bf16 Ks[64 * 64];
    __shared__ __align__(16) bf16 Vs[64 * 64];
    __shared__ __align__(16) bf16 Ps[64 * 64];

    int p0 = w * 1024 + l * 16;
    {
        const char* qg = (const char*)(Qb + (((size_t)bq * HH + h) * SS + qt * QT) * DD);
        #pragma unroll
        for (int i = 0; i < 2; ++i) {
            int p = i * 4096 + p0;
            int row = p >> 7, cb = p & 127;
            int scb = cb ^ ((row & 7) << 4);
            __builtin_amdgcn_global_load_lds((AS1)(qg + row * 128 + scb),
                (AS3)((char*)Qs + i * 4096 + w * 1024), 16, 0, 0);
        }
    }

    float mrun[4], lrun[4];
    f32x4 oacc[4];
    #pragma unroll
    for (int j = 0; j < 4; ++j) { mrun[j] = -3.0e38f; lrun[j] = 0.f; }
    #pragma unroll
    for (int n = 0; n < 4; ++n) oacc[n] = (f32x4){0.f, 0.f, 0.f, 0.f};

    int ntiles = causal ? (qt + 1) : (SS / KT);
    int qrow_base = w * 16;

    for (int kt = 0; kt < ntiles; ++kt) {
        const char* kg = (const char*)(Kb + ((size_t)bh * SS + kt * KT) * DD);
        const char* vg = (const char*)(Vb + (size_t)bh * DD * SS + (size_t)kt * KT);
        #pragma unroll
        for (int i = 0; i < 2; ++i) {
            int p = i * 4096 + p0;
            int row = p >> 7, cb = p & 127;
            int scb = cb ^ ((row & 7) << 4);
            __builtin_amdgcn_global_load_lds((AS1)(kg + row * 128 + scb),
                (AS3)((char*)Ks + i * 4096 + w * 1024), 16, 0, 0);
            __builtin_amdgcn_global_load_lds((AS1)(vg + (size_t)row * (SS * 2) + scb),
                (AS3)((char*)Vs + i * 4096 + w * 1024), 16, 0, 0);
        }
        int km[4];
        if (maskE) {
            #pragma unroll
            for (int n = 0; n < 4; ++n)
                km[n] = maskE[(size_t)bq * SS + kt * KT + n * 16 + lr];
        }
        __syncthreads();

        f32x4 sacc[4];
        #pragma unroll
        for (int n = 0; n < 4; ++n) sacc[n] = (f32x4){0.f, 0.f, 0.f, 0.f};
        #pragma unroll
        for (int ks = 0; ks < 2; ++ks) {
            int qrow = qrow_base + lr;
            s16x8 aq = *(const s16x8*)((const char*)Qs +
                        qrow * 128 + ((ks * 64 + g * 16) ^ ((qrow & 7) << 4)));
            #pragma unroll
            for (int n = 0; n < 4; ++n) {
                int krow = n * 16 + lr;
                s16x8 bk = *(const s16x8*)((const char*)Ks +
                            krow * 128 + ((ks * 64 + g * 16) ^ ((krow & 7) << 4)));
                sacc[n] = __builtin_amdgcn_mfma_f32_16x16x32_bf16(aq, bk, sacc[n], 0, 0, 0);
            }
        }

        #pragma unroll
        for (int n = 0; n < 4; ++n) {
            #pragma unroll
            for (int j = 0; j < 4; ++j) {
                float v = sacc[n][j] * 0.125f;
                if (causal) {
                    if (kt == qt && (n * 16 + lr > qrow_base + 4 * g + j)) v = -3.0e38f;
                } else {
                    if (km[n] != 0) v = -1e4f;
                }
                sacc[n][j] = v;
            }
        }

        float mx[4];
        #pragma unroll
        for (int j = 0; j < 4; ++j)
            mx[j] = fmaxf(fmaxf(sacc[0][j], sacc[1][j]), fmaxf(sacc[2][j], sacc[3][j]));
        #pragma unroll
        for (int msk = 1; msk < 16; msk <<= 1) {
            #pragma unroll
            for (int j = 0; j < 4; ++j) mx[j] = fmaxf(mx[j], __shfl_xor(mx[j], msk));
        }
        float rs[4], psum[4];
        #pragma unroll
        for (int j = 0; j < 4; ++j) {
            float mn = fmaxf(mrun[j], mx[j]);
            rs[j] = __expf(mrun[j] - mn);
            mrun[j] = mn;
            psum[j] = 0.f;
        }
        #pragma unroll
        for (int n = 0; n < 4; ++n) {
            #pragma unroll
            for (int j = 0; j < 4; ++j) {
                float p = __expf(sacc[n][j] - mrun[j]);
                psum[j] += p;
                int prow = qrow_base + 4 * g + j;
                int key = n * 16 + lr;
                *(bf16*)((char*)Ps + prow * 128 + ((2 * key) ^ ((prow & 7) << 4))) =
                    __float2bfloat16(p);
            }
        }
        #pragma unroll
        for (int msk = 1; msk < 16; msk <<= 1) {
            #pragma unroll
            for (int j = 0; j < 4; ++j) psum[j] += __shfl_xor(psum[j], msk);
        }
        #pragma unroll
        for (int j = 0; j < 4; ++j) lrun[j] = lrun[j] * rs[j] + psum[j];
        #pragma unroll
        for (int n = 0; n < 4; ++n) {
            #pragma unroll
            for (int j = 0; j < 4; ++j) oacc[n][j] *= rs[j];
        }

        #pragma unroll
        for (int ks = 0; ks < 2; ++ks) {
            int prow = qrow_base + lr;
            s16x8 ap = *(const s16x8*)((const char*)Ps +
                        prow * 128 + ((ks * 64 + g * 16) ^ ((prow & 7) << 4)));
            #pragma unroll
            for (int n = 0; n < 4; ++n) {
                int vrow = n * 16 + lr;
                s16x8 bv = *(const s16x8*)((const char*)Vs +
                            vrow * 128 + ((ks * 64 + g * 16) ^ ((vrow & 7) << 4)));
                oacc[n] = __builtin_amdgcn_mfma_f32_16x16x32_bf16(ap, bv, oacc[n], 0, 0, 0);
            }
        }
        __syncthreads();
    }

    float inv[4];
    #pragma unroll
    for (int j = 0; j < 4; ++j) inv[j] = 1.0f / lrun[j];
    #pragma unroll
    for (int n = 0; n < 4; ++n) {
        #pragma unroll
        for (int j = 0; j < 4; ++j) {
            int q = qt * QT + qrow_base + 4 * g + j;
            int d = n * 16 + lr;
            Out[((size_t)bp * SS + q) * EE + h * DD + d] =
                __float2bfloat16(oacc[n][j] * inv[j]);
        }
    }
}

// ---------------- fused gate(3 branches) + /sqrt3*maskq + ln2 (bf16 logits) ---------
__global__ __launch_bounds__(256) void gate3ln_kernel(
    const bf16* __restrict__ logits, const float* __restrict__ a,
    const bf16* __restrict__ e, float* __restrict__ acc, bf16* __restrict__ lnout,
    const int* __restrict__ tau, const float* __restrict__ maskq,
    const float* __restrict__ g, const float* __restrict__ bta)
{
    int row = blockIdx.x;
    int tid = threadIdx.x;
    float thr = (float)tau[0];
    float mq = maskq[row] * 0.57735026918962576f;
    size_t base = (size_t)row * EE;

    float aq[3];
    float s1 = 0.f, s2 = 0.f;
    #pragma unroll
    for (int c = 0; c < 3; ++c) {
        size_t i = base + tid + c * 256;
        float av = a[i];
        float r = 0.f;
        #pragma unroll
        for (int idx = 0; idx < 3; ++idx) {
            float lg = __bfloat162float(logits[(size_t)idx * NE + i]);
            float ev = __bfloat162float(e[(size_t)idx * NE + i]);
            float al = 1.0f / (1.0f + __expf(-lg));
            float lm = (al > thr) ? 1.0f : 0.0f;
            float vm = (al < 1.0f - thr) ? 1.0f : 0.0f;
            r += al * lm * av + (1.0f - al) * vm * ev;
        }
        float v = r * mq;
        acc[i] = v;
        aq[c] = v;
        s1 += v;
        s2 += v * v;
    }
    #pragma unroll
    for (int o = 32; o > 0; o >>= 1) {
        s1 += __shfl_down(s1, o);
        s2 += __shfl_down(s2, o);
    }
    __shared__ float r1[4], r2[4];
    if ((tid & 63) == 0) { r1[tid >> 6] = s1; r2[tid >> 6] = s2; }
    __syncthreads();
    float mean = (r1[0] + r1[1] + r1[2] + r1[3]) * (1.0f / 768.0f);
    float ssq  = (r2[0] + r2[1] + r2[2] + r2[3]) * (1.0f / 768.0f);
    float rstd = rsqrtf(ssq - mean * mean + 1e-5f);

    bf16* y = lnout + base;
    #pragma unroll
    for (int c = 0; c < 3; ++c) {
        int col = tid + c * 256;
        y[col] = __float2bfloat16((aq[c] - mean) * rstd * g[col] + bta[col]);
    }
}

extern "C" void kernel_launch(void* const* d_in, const int* in_sizes, int n_in,
                              void* d_out, int out_size, void* d_ws, size_t ws_size,
                              hipStream_t stream)
{
    const float* x        = (const float*)d_in[0];
    const float* enc      = (const float*)d_in[1];
    const float* maskq    = (const float*)d_in[2];
    const int*   mask_enc = (const int*)d_in[4];
    const int*   tau      = (const int*)d_in[6];
    const float* Wq = (const float*)d_in[7];
    const float* Wk = (const float*)d_in[8];
    const float* Wv = (const float*)d_in[9];
    const float* Wo = (const float*)d_in[10];
    const float* bo = (const float*)d_in[11];
    const float* fcq_w = (const float*)d_in[12];
    const float* fcq_b = (const float*)d_in[13];
    const float* fck_w = (const float*)d_in[14];
    const float* fck_b = (const float*)d_in[15];
    const float* fcv_w = (const float*)d_in[16];
    const float* fcv_b = (const float*)d_in[17];
    const float* cproj_w = (const float*)d_in[18];
    const float* cproj_b = (const float*)d_in[19];
    const float* ln1_g = (const float*)d_in[20];
    const float* ln1_b = (const float*)d_in[21];
    const float* ln2_g = (const float*)d_in[22];
    const float* ln2_b = (const float*)d_in[23];
    const float* cfc_w = (const float*)d_in[24];
    const float* cfc_b = (const float*)d_in[25];
    const float* cproj2_w = (const float*)d_in[26];
    const float* cproj2_b = (const float*)d_in[27];
    const float* aw[3] = {(const float*)d_in[28], (const float*)d_in[30], (const float*)d_in[32]};
    const float* ab[3] = {(const float*)d_in[29], (const float*)d_in[31], (const float*)d_in[33]};

    float* out   = (float*)d_out;       // [NTOK, E]
    float* kpres = out + NE;            // present K [B,H,S,D] f32 (V at +NE)
    float* vpres = out + 2 * NE;

    float* ws  = (float*)d_ws;
    float* a     = ws;                  // NE f32
    float* acc   = ws + NE;             // NE f32
    float* R     = ws + 2 * NE;         // 3*NE f32, time-shared
    bf16*  kb_c    = (bf16*)R;
    bf16*  vb_c    = kb_c + 3 * NE;
    bf16*  logitsb = (bf16*)R;          // [3][NE] bf16 (after cross-attn, kb_c dead)
    bf16*  mlphb   = (bf16*)R;

    bf16* bbase = (bf16*)(ws + 5 * NE);
    bf16* lnb   = bbase;
    bf16* atts  = bbase;
    bf16* lnenc = bbase + NE;
    bf16* attc  = lnenc;
    bf16* a_bf  = bbase + 4 * NE;
    bf16* e_bf  = bbase + 5 * NE;
    bf16* qbhb  = bbase + 8 * NE;
    bf16* kbhb  = bbase + 9 * NE;      // written by QKV as Cb+NE
    bf16* vbhb  = bbase + 10 * NE;     // V^T for attention
    bf16* vbhsd = bbase + 11 * NE;     // V BHSD bf16 copy (for present upcast)
    bf16* wp    = bbase + 12 * NE;
    bf16* WqkvT = wp;          wp += 3 * 768 * 768;
    bf16* WoT = wp;            wp += 768 * 768;
    bf16* fcqT = wp;           wp += 768 * 768;
    bf16* fckvT = wp;          wp += 2 * 768 * 768;
    bf16* cprojT = wp;         wp += 768 * 768;
    bf16* awT = wp;            wp += (size_t)3 * 1536 * 768;
    bf16* cfcT = wp;           wp += (size_t)768 * 3072;
    bf16* cproj2T = wp;        wp += (size_t)3072 * 768;
    float* kvb = (float*)wp;
    float* gb  = kvb + 1536;

    dim3 blk(256);

    // 1. ALL weight prep + bias concat, one launch
    tcast_all_kernel<<<12687, blk, 0, stream>>>(
        Wq, Wk, Wv, Wo, fcq_w, fck_w, fcv_w, cproj_w,
        aw[0], aw[1], aw[2], cfc_w, cproj2_w,
        WqkvT, WqkvT + 768 * 768, WqkvT + 2 * 768 * 768, WoT, fcqT,
        fckvT, fckvT + 768 * 768, cprojT,
        awT, awT + 1536 * 768, awT + 2 * 1536 * 768, cfcT, cproj2T,
        fck_b, fcv_b, ab[0], ab[1], ab[2], kvb, gb);
    // 2. LN(x) + LN(enc), one launch
    ln_all_kernel<<<4 * NTOK, blk, 0, stream>>>(x, enc, lnb, lnenc, ln1_g, ln1_b);
    // 3. self-QKV + cross-KV mega GEMM (all-bf16 epilogues)
    qkvkv_kernel<<<1728, blk, 0, stream>>>(lnb, lnenc, WqkvT, fckvT, kvb,
        vbhsd, qbhb, vbhb, kb_c, vb_c);
    // 3b. present K/V f32 upcast (pure output; bf16-rounded, well under threshold)
    present_cast_kernel<<<1536, blk, 0, stream>>>(kbhb, vbhsd, kpres, vpres);
    // 4. causal self-attention
    fattn2_kernel<<<dim3(96, 8), blk, 0, stream>>>(qbhb, kbhb, vbhb, nullptr, atts, 1);
    // 5. a = attout@Wo + bo + x
    mgemm_kernel<FLAG_RES><<<dim3(32, 6), blk, 0, stream>>>(atts, nullptr, WoT, bo,
        a, a_bf, nullptr, 768, x, nullptr, 768, 768, 768);
    // 6. al = ln1(a)
    ln_kernel<<<NTOK, blk, 0, stream>>>(a, lnb, ln1_g, ln1_b);
    // 7. cross q
    mgemm_kernel<FLAG_CBSD><<<dim3(32, 6), blk, 0, stream>>>(lnb, nullptr, fcqT, fcq_b,
        nullptr, qbhb, nullptr, 0, nullptr, nullptr, 768, 768, 768);
    // 8. cross attention (batched over 3 encoders)
    fattn2_kernel<<<dim3(288, 8), blk, 0, stream>>>(qbhb, kb_c, vb_c, mask_enc, attc, 0);
    // 9. e = attout@cproj + b
    mgemm_kernel<0><<<dim3(96, 6), blk, 0, stream>>>(attc, nullptr, cprojT, cproj_b,
        nullptr, e_bf, nullptr, 768, nullptr, nullptr, 768, 768, 768);
    // 10. gate logits (bf16 out)
    mgemm_kernel<FLAG_GSEG><<<dim3(96, 6), blk, 0, stream>>>(a_bf, e_bf, awT, gb,
        nullptr, logitsb, nullptr, 768, nullptr, nullptr, 768, 1536, 768);
    // 11. gate + ln2
    gate3ln_kernel<<<NTOK, blk, 0, stream>>>(logitsb, a, e_bf, acc, lnb,
        tau, maskq, ln2_g, ln2_b);
    // 12-13. MLP
    mgemm_kernel<FLAG_GELU><<<dim3(32, 24), blk, 0, stream>>>(lnb, nullptr, cfcT, cfc_b,
        nullptr, mlphb, nullptr, 3072, nullptr, nullptr, 3072, 768, 768);
    mgemm_kernel<FLAG_FIN><<<dim3(32, 6), blk, 0, stream>>>(mlphb, nullptr, cproj2T, cproj2_b,
        out, nullptr, nullptr, 0, acc, maskq, 768, 3072, 3072);
}